// Round 2
// baseline (161.035 us; speedup 1.0000x reference)
//
#include <hip/hip_runtime.h>
#include <math.h>

typedef float f4 __attribute__((ext_vector_type(4)));
typedef float f2 __attribute__((ext_vector_type(2)));

__constant__ float c_ytab[64] = {
  16.f,11.f,10.f,16.f,24.f,40.f,51.f,61.f,
  12.f,12.f,14.f,19.f,26.f,58.f,60.f,55.f,
  14.f,13.f,16.f,24.f,40.f,57.f,69.f,56.f,
  14.f,17.f,22.f,29.f,51.f,87.f,80.f,62.f,
  18.f,22.f,37.f,56.f,68.f,109.f,103.f,77.f,
  24.f,35.f,55.f,64.f,81.f,104.f,113.f,92.f,
  49.f,64.f,78.f,87.f,103.f,121.f,120.f,101.f,
  72.f,92.f,95.f,98.f,112.f,100.f,103.f,99.f};

__constant__ float c_ctab[64] = {
  17.f,18.f,24.f,47.f,99.f,99.f,99.f,99.f,
  18.f,21.f,26.f,66.f,99.f,99.f,99.f,99.f,
  24.f,26.f,56.f,99.f,99.f,99.f,99.f,99.f,
  47.f,66.f,99.f,99.f,99.f,99.f,99.f,99.f,
  99.f,99.f,99.f,99.f,99.f,99.f,99.f,99.f,
  99.f,99.f,99.f,99.f,99.f,99.f,99.f,99.f,
  99.f,99.f,99.f,99.f,99.f,99.f,99.f,99.f,
  99.f,99.f,99.f,99.f,99.f,99.f,99.f,99.f};

// One block = 64x16 pixel tile of one image (H=W=512):
//   16 Y 8x8 blocks (2 rows x 8 cols), 4 Cb + 4 Cr 8x8 blocks (pooled 8x32).
// Chroma 2x2 pooling done in-register via __shfl_xor(16) (rows t>>4 pair as
// t^16 within one wave). 2 barriers total.
__global__ __launch_bounds__(256) void jpeg_kernel(
    const float* __restrict__ x, const float* __restrict__ factor,
    float* __restrict__ out, int B)
{
    __shared__ float s_y [16][68];   // Y pixels (64 wide, +4 pad; rows 16B-aligned)
    __shared__ float s_cp[2][8][36]; // pooled chroma 8x32 (+4 pad; rows 16B-aligned)
    __shared__ float s_ty[16][72];   // Y DCT pass-1 temp: [blk][x*9+v]
    __shared__ float s_tc[2][4][72]; // chroma DCT pass-1 temp
    __shared__ float s_C [8][9];     // cos basis C[y][v] = cos((2y+1)v*pi/16)
    __shared__ float s_qy[64];       // 1/(Y_TABLE*f)
    __shared__ float s_qc[64];       // 1/(C_TABLE*f)

    const int t      = threadIdx.x;
    const int b      = blockIdx.x >> 8;    // image (256 tiles/image)
    const int rem    = blockIdx.x & 255;
    const int tile_y = rem >> 3;           // 0..31
    const int tile_x = rem & 7;            // 0..7

    const float f = factor[b];
    if (t < 64) {
        int yy = t >> 3, vv = t & 7;
        s_C[yy][vv] = cosf((float)((2*yy+1)*vv) * 0.19634954084936207f); // pi/16
    } else if (t < 128) {
        s_qy[t - 64] = 1.0f / (c_ytab[t - 64] * f);
    } else if (t < 192) {
        s_qc[t - 128] = 1.0f / (c_ctab[t - 128] * f);
    }

    // ---- Phase A: load, RGB->YCbCr, Y->LDS, chroma pool in-register --------
    {
        const int row = t >> 4;            // 0..15
        const int col = (t & 15) << 2;     // 0..60
        const int gy  = tile_y * 16 + row;
        const int gx  = (tile_x << 6) + col;
        const float* px = x + ((size_t)b * 3 * 512 + gy) * 512 + gx;
        f4 r4 = *(const f4*)(px);
        f4 g4 = *(const f4*)(px + 262144);
        f4 b4 = *(const f4*)(px + 524288);
        f4 yv, cbv, crv;
        #define CC(i) { \
            float R = r4[i]*255.0f, G = g4[i]*255.0f, Bl = b4[i]*255.0f; \
            yv[i]  =  0.299f*R + 0.587f*G + 0.114f*Bl; \
            cbv[i] = -0.168736f*R - 0.331264f*G + 0.5f*Bl + 128.0f; \
            crv[i] =  0.5f*R - 0.418688f*G - 0.081312f*Bl + 128.0f; }
        CC(0); CC(1); CC(2); CC(3);
        #undef CC
        *(f4*)&s_y[row][col] = yv;
        // horizontal pair sums
        float cb01 = cbv[0] + cbv[1], cb23 = cbv[2] + cbv[3];
        float cr01 = crv[0] + crv[1], cr23 = crv[2] + crv[3];
        // vertical partner: lane t^16 is row^1, same cols, same wave
        float cb01o = __shfl_xor(cb01, 16, 64);
        float cb23o = __shfl_xor(cb23, 16, 64);
        float cr01o = __shfl_xor(cr01, 16, 64);
        float cr23o = __shfl_xor(cr23, 16, 64);
        if ((row & 1) == 0) {
            int prow = row >> 1;           // 0..7
            int pcol = (t & 15) << 1;      // 0..30
            f2 cbp = { 0.25f*(cb01 + cb01o), 0.25f*(cb23 + cb23o) };
            f2 crp = { 0.25f*(cr01 + cr01o), 0.25f*(cr23 + cr23o) };
            *(f2*)&s_cp[0][prow][pcol] = cbp;
            *(f2*)&s_cp[1][prow][pcol] = crp;
        }
    }
    __syncthreads();

    // ---- Phase B: DCT pass 1 (rows -> v) for Y and chroma ------------------
    {   // Y: 4 of 1024 tmp elements per thread
        int blk = t >> 4;                  // 0..15
        int xx  = (t >> 1) & 7;
        int v0  = (t & 1) << 2;            // 0 or 4
        int by = blk >> 3, bx = blk & 7;
        const float* ar = &s_y[by*8 + xx][bx*8];
        f4 q0 = *(const f4*)ar;
        f4 q1 = *(const f4*)(ar + 4);
        float a[8] = {q0[0]-128.f, q0[1]-128.f, q0[2]-128.f, q0[3]-128.f,
                      q1[0]-128.f, q1[1]-128.f, q1[2]-128.f, q1[3]-128.f};
        #pragma unroll
        for (int k = 0; k < 4; ++k) {
            int v = v0 + k;
            float s = 0.f;
            #pragma unroll
            for (int j = 0; j < 8; ++j) s += a[j] * s_C[j][v];
            s_ty[blk][xx*9 + v] = s;
        }
    }
    {   // chroma: 2 of 256 tmp elements per channel per thread
        int ch  = t >> 7;
        int tt  = t & 127;
        int blk = tt >> 5;                 // 0..3
        int xx  = (tt >> 2) & 7;
        int v0  = (tt & 3) << 1;           // 0,2,4,6
        const float* ar = &s_cp[ch][xx][blk*8];
        f4 q0 = *(const f4*)ar;
        f4 q1 = *(const f4*)(ar + 4);
        float a[8] = {q0[0]-128.f, q0[1]-128.f, q0[2]-128.f, q0[3]-128.f,
                      q1[0]-128.f, q1[1]-128.f, q1[2]-128.f, q1[3]-128.f};
        #pragma unroll
        for (int k = 0; k < 2; ++k) {
            int v = v0 + k;
            float s = 0.f;
            #pragma unroll
            for (int j = 0; j < 8; ++j) s += a[j] * s_C[j][v];
            s_tc[ch][blk][xx*9 + v] = s;
        }
    }
    __syncthreads();

    // ---- Phase C: DCT pass 2 (cols -> u), quantize, diff_round, store -----
    {   // Y: 4 outputs per thread, float4 store
        int blk = t >> 4;
        int u   = (t >> 1) & 7;
        int v0  = (t & 1) << 2;
        int by = blk >> 3, bx = blk & 7;
        float au = (u == 0) ? 0.70710678118654752f : 1.0f;
        f4 res;
        #pragma unroll
        for (int k = 0; k < 4; ++k) {
            int v = v0 + k;
            float s = 0.f;
            #pragma unroll
            for (int j = 0; j < 8; ++j) s += s_C[j][u] * s_ty[blk][j*9 + v];
            float av   = (v == 0) ? 0.70710678118654752f : 1.0f;
            float q    = s * (au * av * 0.25f) * s_qy[u*8 + v];
            float r    = rintf(q);          // round-half-even == jnp.round
            float d    = q - r;
            res[k] = r + d * d * d;         // diff_round
        }
        size_t n = (size_t)b * 4096 + (size_t)(tile_y*2 + by) * 64 + (tile_x*8 + bx);
        *(f4*)(out + n * 64 + u*8 + v0) = res;
    }
    if (t < 128) {  // chroma: waves 0-1, 4 outputs per thread, float4 store
        int ch  = t >> 6;                  // 0=cb, 1=cr
        int tt  = t & 63;
        int blk = tt >> 4;                 // 0..3
        int u   = (tt >> 1) & 7;
        int v0  = (tt & 1) << 2;           // 0 or 4
        float au = (u == 0) ? 0.70710678118654752f : 1.0f;
        f4 res;
        #pragma unroll
        for (int k = 0; k < 4; ++k) {
            int v = v0 + k;
            float s = 0.f;
            #pragma unroll
            for (int j = 0; j < 8; ++j) s += s_C[j][u] * s_tc[ch][blk][j*9 + v];
            float av   = (v == 0) ? 0.70710678118654752f : 1.0f;
            float q    = s * (au * av * 0.25f) * s_qc[u*8 + v];
            float r    = rintf(q);
            float d    = q - r;
            res[k] = r + d * d * d;
        }
        size_t base = (size_t)B * 262144 + (size_t)ch * (size_t)B * 65536;
        size_t n    = (size_t)b * 1024 + tile_y * 32 + tile_x * 4 + blk;
        *(f4*)(out + base + n * 64 + u*8 + v0) = res;
    }
}

extern "C" void kernel_launch(void* const* d_in, const int* in_sizes, int n_in,
                              void* d_out, int out_size, void* d_ws, size_t ws_size,
                              hipStream_t stream) {
    const float* x      = (const float*)d_in[0];
    const float* factor = (const float*)d_in[1];
    float* out          = (float*)d_out;
    const int B = in_sizes[1];
    dim3 grid(B * 256), block(256);
    jpeg_kernel<<<grid, block, 0, stream>>>(x, factor, out, B);
}

// Round 3
// 153.796 us; speedup vs baseline: 1.0471x; 1.0471x over previous
//
#include <hip/hip_runtime.h>
#include <math.h>

typedef float f4 __attribute__((ext_vector_type(4)));
typedef float f2 __attribute__((ext_vector_type(2)));

__constant__ float c_ytab[64] = {
  16.f,11.f,10.f,16.f,24.f,40.f,51.f,61.f,
  12.f,12.f,14.f,19.f,26.f,58.f,60.f,55.f,
  14.f,13.f,16.f,24.f,40.f,57.f,69.f,56.f,
  14.f,17.f,22.f,29.f,51.f,87.f,80.f,62.f,
  18.f,22.f,37.f,56.f,68.f,109.f,103.f,77.f,
  24.f,35.f,55.f,64.f,81.f,104.f,113.f,92.f,
  49.f,64.f,78.f,87.f,103.f,121.f,120.f,101.f,
  72.f,92.f,95.f,98.f,112.f,100.f,103.f,99.f};

__constant__ float c_ctab[64] = {
  17.f,18.f,24.f,47.f,99.f,99.f,99.f,99.f,
  18.f,21.f,26.f,66.f,99.f,99.f,99.f,99.f,
  24.f,26.f,56.f,99.f,99.f,99.f,99.f,99.f,
  47.f,66.f,99.f,99.f,99.f,99.f,99.f,99.f,
  99.f,99.f,99.f,99.f,99.f,99.f,99.f,99.f,
  99.f,99.f,99.f,99.f,99.f,99.f,99.f,99.f,
  99.f,99.f,99.f,99.f,99.f,99.f,99.f,99.f,
  99.f,99.f,99.f,99.f,99.f,99.f,99.f,99.f};

// One block = 64x16 pixel tile of one image (H=W=512):
//   16 Y 8x8 blocks (2 rows x 8 cols), 4 Cb + 4 Cr 8x8 blocks (pooled 8x32).
// Chroma 2x2 pooling in-register via __shfl_xor(16). 2 barriers.
// All global accesses nontemporal: pure streaming, zero reuse.
__global__ __launch_bounds__(256) void jpeg_kernel(
    const float* __restrict__ x, const float* __restrict__ factor,
    float* __restrict__ out, int B)
{
    __shared__ float s_y [16][68];   // Y pixels (64 wide, +4 pad; rows 16B-aligned)
    __shared__ float s_cp[2][8][36]; // pooled chroma 8x32 (+4 pad)
    __shared__ float s_ty[16][72];   // Y DCT pass-1 temp: [blk][x*9+v]
    __shared__ float s_tc[2][4][72]; // chroma DCT pass-1 temp
    __shared__ float s_C [8][9];     // cos basis C[y][v] = cos((2y+1)v*pi/16)
    __shared__ float s_qy[64];       // 1/(Y_TABLE*f)
    __shared__ float s_qc[64];       // 1/(C_TABLE*f)

    const int t      = threadIdx.x;
    const int b      = blockIdx.x >> 8;    // image (256 tiles/image)
    const int rem    = blockIdx.x & 255;
    const int tile_y = rem >> 3;           // 0..31
    const int tile_x = rem & 7;            // 0..7

    const float f = factor[b];
    if (t < 64) {
        int yy = t >> 3, vv = t & 7;
        s_C[yy][vv] = cosf((float)((2*yy+1)*vv) * 0.19634954084936207f); // pi/16
    } else if (t < 128) {
        s_qy[t - 64] = 1.0f / (c_ytab[t - 64] * f);
    } else if (t < 192) {
        s_qc[t - 128] = 1.0f / (c_ctab[t - 128] * f);
    }

    // ---- Phase A: load (nt), RGB->YCbCr, Y->LDS, chroma pool in-register ---
    {
        const int row = t >> 4;            // 0..15
        const int col = (t & 15) << 2;     // 0..60
        const int gy  = tile_y * 16 + row;
        const int gx  = (tile_x << 6) + col;
        const float* px = x + ((size_t)b * 3 * 512 + gy) * 512 + gx;
        f4 r4 = __builtin_nontemporal_load((const f4*)(px));
        f4 g4 = __builtin_nontemporal_load((const f4*)(px + 262144));
        f4 b4 = __builtin_nontemporal_load((const f4*)(px + 524288));
        f4 yv, cbv, crv;
        #define CC(i) { \
            float R = r4[i]*255.0f, G = g4[i]*255.0f, Bl = b4[i]*255.0f; \
            yv[i]  =  0.299f*R + 0.587f*G + 0.114f*Bl; \
            cbv[i] = -0.168736f*R - 0.331264f*G + 0.5f*Bl + 128.0f; \
            crv[i] =  0.5f*R - 0.418688f*G - 0.081312f*Bl + 128.0f; }
        CC(0); CC(1); CC(2); CC(3);
        #undef CC
        *(f4*)&s_y[row][col] = yv;
        float cb01 = cbv[0] + cbv[1], cb23 = cbv[2] + cbv[3];
        float cr01 = crv[0] + crv[1], cr23 = crv[2] + crv[3];
        float cb01o = __shfl_xor(cb01, 16, 64);
        float cb23o = __shfl_xor(cb23, 16, 64);
        float cr01o = __shfl_xor(cr01, 16, 64);
        float cr23o = __shfl_xor(cr23, 16, 64);
        if ((row & 1) == 0) {
            int prow = row >> 1;           // 0..7
            int pcol = (t & 15) << 1;      // 0..30
            f2 cbp = { 0.25f*(cb01 + cb01o), 0.25f*(cb23 + cb23o) };
            f2 crp = { 0.25f*(cr01 + cr01o), 0.25f*(cr23 + cr23o) };
            *(f2*)&s_cp[0][prow][pcol] = cbp;
            *(f2*)&s_cp[1][prow][pcol] = crp;
        }
    }
    __syncthreads();

    // ---- Phase B: DCT pass 1 (rows -> v) for Y and chroma ------------------
    {   // Y: 4 of 1024 tmp elements per thread
        int blk = t >> 4;                  // 0..15
        int xx  = (t >> 1) & 7;
        int v0  = (t & 1) << 2;            // 0 or 4
        int by = blk >> 3, bx = blk & 7;
        const float* ar = &s_y[by*8 + xx][bx*8];
        f4 q0 = *(const f4*)ar;
        f4 q1 = *(const f4*)(ar + 4);
        float a[8] = {q0[0]-128.f, q0[1]-128.f, q0[2]-128.f, q0[3]-128.f,
                      q1[0]-128.f, q1[1]-128.f, q1[2]-128.f, q1[3]-128.f};
        #pragma unroll
        for (int k = 0; k < 4; ++k) {
            int v = v0 + k;
            float s = 0.f;
            #pragma unroll
            for (int j = 0; j < 8; ++j) s += a[j] * s_C[j][v];
            s_ty[blk][xx*9 + v] = s;
        }
    }
    {   // chroma: 2 of 256 tmp elements per channel per thread
        int ch  = t >> 7;
        int tt  = t & 127;
        int blk = tt >> 5;                 // 0..3
        int xx  = (tt >> 2) & 7;
        int v0  = (tt & 3) << 1;           // 0,2,4,6
        const float* ar = &s_cp[ch][xx][blk*8];
        f4 q0 = *(const f4*)ar;
        f4 q1 = *(const f4*)(ar + 4);
        float a[8] = {q0[0]-128.f, q0[1]-128.f, q0[2]-128.f, q0[3]-128.f,
                      q1[0]-128.f, q1[1]-128.f, q1[2]-128.f, q1[3]-128.f};
        #pragma unroll
        for (int k = 0; k < 2; ++k) {
            int v = v0 + k;
            float s = 0.f;
            #pragma unroll
            for (int j = 0; j < 8; ++j) s += a[j] * s_C[j][v];
            s_tc[ch][blk][xx*9 + v] = s;
        }
    }
    __syncthreads();

    // ---- Phase C: DCT pass 2 (cols -> u), quantize, diff_round, store (nt) -
    {   // Y: 4 outputs per thread, float4 store
        int blk = t >> 4;
        int u   = (t >> 1) & 7;
        int v0  = (t & 1) << 2;
        int by = blk >> 3, bx = blk & 7;
        float au = (u == 0) ? 0.70710678118654752f : 1.0f;
        f4 res;
        #pragma unroll
        for (int k = 0; k < 4; ++k) {
            int v = v0 + k;
            float s = 0.f;
            #pragma unroll
            for (int j = 0; j < 8; ++j) s += s_C[j][u] * s_ty[blk][j*9 + v];
            float av   = (v == 0) ? 0.70710678118654752f : 1.0f;
            float q    = s * (au * av * 0.25f) * s_qy[u*8 + v];
            float r    = rintf(q);          // round-half-even == jnp.round
            float d    = q - r;
            res[k] = r + d * d * d;         // diff_round
        }
        size_t n = (size_t)b * 4096 + (size_t)(tile_y*2 + by) * 64 + (tile_x*8 + bx);
        __builtin_nontemporal_store(res, (f4*)(out + n * 64 + u*8 + v0));
    }
    if (t < 128) {  // chroma: waves 0-1, 4 outputs per thread, float4 store
        int ch  = t >> 6;                  // 0=cb, 1=cr
        int tt  = t & 63;
        int blk = tt >> 4;                 // 0..3
        int u   = (tt >> 1) & 7;
        int v0  = (tt & 1) << 2;           // 0 or 4
        float au = (u == 0) ? 0.70710678118654752f : 1.0f;
        f4 res;
        #pragma unroll
        for (int k = 0; k < 4; ++k) {
            int v = v0 + k;
            float s = 0.f;
            #pragma unroll
            for (int j = 0; j < 8; ++j) s += s_C[j][u] * s_tc[ch][blk][j*9 + v];
            float av   = (v == 0) ? 0.70710678118654752f : 1.0f;
            float q    = s * (au * av * 0.25f) * s_qc[u*8 + v];
            float r    = rintf(q);
            float d    = q - r;
            res[k] = r + d * d * d;
        }
        size_t base = (size_t)B * 262144 + (size_t)ch * (size_t)B * 65536;
        size_t n    = (size_t)b * 1024 + tile_y * 32 + tile_x * 4 + blk;
        __builtin_nontemporal_store(res, (f4*)(out + base + n * 64 + u*8 + v0));
    }
}

extern "C" void kernel_launch(void* const* d_in, const int* in_sizes, int n_in,
                              void* d_out, int out_size, void* d_ws, size_t ws_size,
                              hipStream_t stream) {
    const float* x      = (const float*)d_in[0];
    const float* factor = (const float*)d_in[1];
    float* out          = (float*)d_out;
    const int B = in_sizes[1];
    dim3 grid(B * 256), block(256);
    jpeg_kernel<<<grid, block, 0, stream>>>(x, factor, out, B);
}